// Round 6
// baseline (95.342 us; speedup 1.0000x reference)
//
#include <hip/hip_runtime.h>
#include <cstdint>

#define NV 200000
#define NCOLS 5
#define P 128
#define NE 8192
#define NC 1024

// Kernel 1: gather all clusters' coords once into dense float4 array.
// ws[c*P + p] = (data[v,1], data[v,2], data[v,3], 0) where v = clusts[c,p].
__global__ __launch_bounds__(256) void gather_kernel(
    const float* __restrict__ data,
    const int*   __restrict__ clusts,
    float4*      __restrict__ ws)
{
    const int idx = blockIdx.x * 256 + threadIdx.x;   // 0 .. NC*P-1
    const int v = clusts[idx];
    ws[idx] = make_float4(data[v * NCOLS + 1], data[v * NCOLS + 2],
                          data[v * NCOLS + 3], 0.f);
}

// Edge kernel: ONE WAVE PER EDGE (128-thread block = 2 waves = 2 edges).
//
// Ladder so far (edge-kernel time, back-solved from totals):
//   R3 serial chain, 32 VGPR, 8 waves/SIMD:        42.0 us  (latency: 256-link cmp chain)
//   R4 8 chains, full unroll, 216 VGPR, 2 waves:   73.0 us  (occupancy collapse)
//   R5 8 chains, groups of 8, ~100+ VGPR, ~4 waves: ~38.6 us
// This version: 8 chains + groups of FOUR a-points -> ~70 VGPR -> ~7
// waves/SIMD. Tests the last quadrant: high ILP AND high occupancy.
//
// Tie-break exactness (HW-proven in R5): within chain m, j = tj+16m fixed,
// k ascends (kk outer asc, u inner asc) => flat ascends; strict < keeps
// first (smallest-flat) min. Cross-chain (m asc) and cross-lane combines
// use packed (d2_bits<<32 | flat) u64 keys => lexicographic
// (min d2, then min flat), bit-identical to jnp.argmin.
//
// No __syncthreads: each wave writes and reads only its own LDS half.
template <bool USE_WS>
__global__ __launch_bounds__(128) void clust_geo_edge_kernel(
    const float*  __restrict__ data,
    const int*    __restrict__ clusts,
    const int*    __restrict__ edge_index,
    const float4* __restrict__ ws,
    float*        __restrict__ out)
{
    const int w    = threadIdx.x >> 6;     // wave id within block: 0/1
    const int lane = threadIdx.x & 63;
    const int e    = blockIdx.x * 2 + w;   // one edge per wave

    __shared__ float4 x1s[2][P];
    __shared__ float4 x2s[2][P];

    const int c1 = edge_index[e];
    const int c2 = edge_index[NE + e];

    // Stage both clusters (4 float4 loads/lane, coalesced on the ws path).
    if (USE_WS) {
        x1s[w][lane]      = ws[c1 * P + lane];
        x1s[w][lane + 64] = ws[c1 * P + lane + 64];
        x2s[w][lane]      = ws[c2 * P + lane];
        x2s[w][lane + 64] = ws[c2 * P + lane + 64];
    } else {
        int v = clusts[c1 * P + lane];
        x1s[w][lane]      = make_float4(data[v * NCOLS + 1], data[v * NCOLS + 2],
                                        data[v * NCOLS + 3], 0.f);
        v = clusts[c1 * P + lane + 64];
        x1s[w][lane + 64] = make_float4(data[v * NCOLS + 1], data[v * NCOLS + 2],
                                        data[v * NCOLS + 3], 0.f);
        v = clusts[c2 * P + lane];
        x2s[w][lane]      = make_float4(data[v * NCOLS + 1], data[v * NCOLS + 2],
                                        data[v * NCOLS + 3], 0.f);
        v = clusts[c2 * P + lane + 64];
        x2s[w][lane + 64] = make_float4(data[v * NCOLS + 1], data[v * NCOLS + 2],
                                        data[v * NCOLS + 3], 0.f);
    }
    // (no barrier needed — per-wave-private LDS halves)

    // 4x16 lane grid: i = ti + 4*k (k=0..31), j = tj + 16*m (m=0..7).
    const int tj = lane & 15;
    const int ti = lane >> 4;

    // b tile resident as scalars (24 VGPR, no dead .w lane).
    float bx[8], by[8], bz[8];
    #pragma unroll
    for (int m = 0; m < 8; ++m) {
        const float4 v = x2s[w][tj + 16 * m];
        bx[m] = v.x; by[m] = v.y; bz[m] = v.z;
    }

    // Eight independent (value, k-index) min-chains.
    float bd[8];
    int   bk[8];
    #pragma unroll
    for (int m = 0; m < 8; ++m) { bd[m] = __builtin_inff(); bk[m] = 0; }

    // Exact replication of reference fp32 arithmetic: (dx*dx + dy*dy) + dz*dz,
    // no FMA contraction (argmin tie-breaking must match numpy).
    // Groups of 4 a-points: only 12 live a-VGPRs, bounding total register
    // pressure to ~70 so ~7 waves/SIMD stay resident; 32 independent pair
    // computations per group keep the issue pipe fed.
    #pragma unroll 1
    for (int kk = 0; kk < 8; ++kk) {
        float ax[4], ay[4], az[4];
        #pragma unroll
        for (int u = 0; u < 4; ++u) {
            const float4 av = x1s[w][ti + 4 * (kk * 4 + u)];   // broadcast read
            ax[u] = av.x; ay[u] = av.y; az[u] = av.z;
        }
        #pragma unroll
        for (int u = 0; u < 4; ++u) {
            #pragma unroll
            for (int m = 0; m < 8; ++m) {
                const float dx = __fsub_rn(ax[u], bx[m]);
                const float dy = __fsub_rn(ay[u], by[m]);
                const float dz = __fsub_rn(az[u], bz[m]);
                const float d2 = __fadd_rn(__fadd_rn(__fmul_rn(dx, dx), __fmul_rn(dy, dy)),
                                           __fmul_rn(dz, dz));
                if (d2 < bd[m]) { bd[m] = d2; bk[m] = kk * 4 + u; }  // k ascending
            }
        }
    }

    // Combine the 8 chains exactly via packed (d2, flat) keys.
    const int base = ti * P + tj;
    unsigned long long key = 0xffffffffffffffffull;
    #pragma unroll
    for (int m = 0; m < 8; ++m) {
        const unsigned flat = (unsigned)(base + (m << 4) + (bk[m] << 9)); // +512*k
        const unsigned long long km =
            ((unsigned long long)__float_as_uint(bd[m]) << 32) | flat;
        if (km < key) key = km;
    }

    // Wave-level (64-lane) min reduce — no cross-wave stage needed.
    for (int off = 32; off > 0; off >>= 1) {
        unsigned long long other = __shfl_down(key, off, 64);
        if (other < key) key = other;
    }

    if (lane == 0) {
        const int flat = (int)(key & 0xffffffffull);
        const int i1 = flat >> 7;
        const int i2 = flat & (P - 1);

        const float v1x = x1s[w][i1].x, v1y = x1s[w][i1].y, v1z = x1s[w][i1].z;
        const float v2x = x2s[w][i2].x, v2y = x2s[w][i2].y, v2z = x2s[w][i2].z;

        const float dx = v1x - v2x, dy = v1y - v2y, dz = v1z - v2z;
        const float lend = sqrtf(dx * dx + dy * dy + dz * dz);

        float nx, ny, nz;
        if (lend > 0.f) { nx = dx / lend; ny = dy / lend; nz = dz / lend; }
        else            { nx = dx;        ny = dy;        nz = dz;        }

        const float B0 = nx * nx, B1 = nx * ny, B2 = nx * nz;
        const float B3 = ny * nx, B4 = ny * ny, B5 = ny * nz;
        const float B6 = nz * nx, B7 = nz * ny, B8 = nz * nz;

        // Row layout (38 floats): [v1 v2 n lend B] [v2 v1 -n lend B].
        // 152-byte rows are 8-aligned every row -> float2 stores are safe.
        float2* o = reinterpret_cast<float2*>(out + (size_t)e * 38);
        o[0]  = make_float2(v1x, v1y);
        o[1]  = make_float2(v1z, v2x);
        o[2]  = make_float2(v2y, v2z);
        o[3]  = make_float2(nx,  ny);
        o[4]  = make_float2(nz,  lend);
        o[5]  = make_float2(B0,  B1);
        o[6]  = make_float2(B2,  B3);
        o[7]  = make_float2(B4,  B5);
        o[8]  = make_float2(B6,  B7);
        o[9]  = make_float2(B8,  v2x);
        o[10] = make_float2(v2y, v2z);
        o[11] = make_float2(v1x, v1y);
        o[12] = make_float2(v1z, -nx);
        o[13] = make_float2(-ny, -nz);
        o[14] = make_float2(lend, B0);
        o[15] = make_float2(B1,  B2);
        o[16] = make_float2(B3,  B4);
        o[17] = make_float2(B5,  B6);
        o[18] = make_float2(B7,  B8);
    }
}

extern "C" void kernel_launch(void* const* d_in, const int* in_sizes, int n_in,
                              void* d_out, int out_size, void* d_ws, size_t ws_size,
                              hipStream_t stream) {
    const float* data       = (const float*)d_in[0];
    const int*   clusts     = (const int*)d_in[1];
    const int*   edge_index = (const int*)d_in[2];
    float*       out        = (float*)d_out;
    float4*      ws         = (float4*)d_ws;

    const size_t need = (size_t)NC * P * sizeof(float4);  // 2 MB
    if (ws_size >= need) {
        gather_kernel<<<(NC * P) / 256, 256, 0, stream>>>(data, clusts, ws);
        clust_geo_edge_kernel<true><<<NE / 2, 128, 0, stream>>>(data, clusts, edge_index, ws, out);
    } else {
        clust_geo_edge_kernel<false><<<NE / 2, 128, 0, stream>>>(data, clusts, edge_index, ws, out);
    }
}

// Round 7
// 93.253 us; speedup vs baseline: 1.0224x; 1.0224x over previous
//
#include <hip/hip_runtime.h>
#include <cstdint>

#define NV 200000
#define NCOLS 5
#define P 128
#define NE 8192
#define NC 1024

typedef float f2 __attribute__((ext_vector_type(2)));

// Kernel 1: gather all clusters' coords once into dense float4 array.
// ws[c*P + p] = (data[v,1], data[v,2], data[v,3], 0) where v = clusts[c,p].
__global__ __launch_bounds__(256) void gather_kernel(
    const float* __restrict__ data,
    const int*   __restrict__ clusts,
    float4*      __restrict__ ws)
{
    const int idx = blockIdx.x * 256 + threadIdx.x;   // 0 .. NC*P-1
    const int v = clusts[idx];
    ws[idx] = make_float4(data[v * NCOLS + 1], data[v * NCOLS + 2],
                          data[v * NCOLS + 3], 0.f);
}

// Edge kernel: ONE WAVE PER EDGE (128-thread block = 2 waves = 2 edges).
//
// R0-R6 established: edge time is pinned at ~38-40 us across occupancy
// 2..8 waves/SIMD and serial vs 8-way-ILP min chains — duty ~53% is
// structure-invariant. This round attacks the only untouched axis: op
// count, via gfx950 packed FP32 (v_pk_add_f32 / v_pk_mul_f32, dual
// IEEE-rn f32 per instruction). The m-loop is packed 2-wide on float2:
// 8 packed ops + 6 scalar track per TWO pairs = 7 issue slots/pair
// (was 11). Packed ops compute each component with the same rn rounding
// as the scalar ops, and `#pragma clang fp contract(off)` forbids FMA
// fusion, so every d2 is bit-identical to the reference chain
// (dx*dx + dy*dy) + dz*dz.
//
// Tie-break exactness (HW-proven in R5): chains are independent per m,
// so packing (m, m+1) per op changes no within-chain ordering; k ascends
// (kk outer asc, u inner asc) => flat ascends per chain; strict < keeps
// first (smallest-flat) min. Cross-chain and cross-lane combines use
// packed (d2_bits<<32 | flat) u64 keys => lexicographic (min d2, then
// min flat), bit-identical to jnp.argmin.
//
// No __syncthreads: each wave writes and reads only its own LDS half.
template <bool USE_WS>
__global__ __launch_bounds__(128) void clust_geo_edge_kernel(
    const float*  __restrict__ data,
    const int*    __restrict__ clusts,
    const int*    __restrict__ edge_index,
    const float4* __restrict__ ws,
    float*        __restrict__ out)
{
#pragma clang fp contract(off)
    const int w    = threadIdx.x >> 6;     // wave id within block: 0/1
    const int lane = threadIdx.x & 63;
    const int e    = blockIdx.x * 2 + w;   // one edge per wave

    __shared__ float4 x1s[2][P];
    __shared__ float4 x2s[2][P];

    const int c1 = edge_index[e];
    const int c2 = edge_index[NE + e];

    // Stage both clusters (4 float4 loads/lane, coalesced on the ws path).
    if (USE_WS) {
        x1s[w][lane]      = ws[c1 * P + lane];
        x1s[w][lane + 64] = ws[c1 * P + lane + 64];
        x2s[w][lane]      = ws[c2 * P + lane];
        x2s[w][lane + 64] = ws[c2 * P + lane + 64];
    } else {
        int v = clusts[c1 * P + lane];
        x1s[w][lane]      = make_float4(data[v * NCOLS + 1], data[v * NCOLS + 2],
                                        data[v * NCOLS + 3], 0.f);
        v = clusts[c1 * P + lane + 64];
        x1s[w][lane + 64] = make_float4(data[v * NCOLS + 1], data[v * NCOLS + 2],
                                        data[v * NCOLS + 3], 0.f);
        v = clusts[c2 * P + lane];
        x2s[w][lane]      = make_float4(data[v * NCOLS + 1], data[v * NCOLS + 2],
                                        data[v * NCOLS + 3], 0.f);
        v = clusts[c2 * P + lane + 64];
        x2s[w][lane + 64] = make_float4(data[v * NCOLS + 1], data[v * NCOLS + 2],
                                        data[v * NCOLS + 3], 0.f);
    }
    // (no barrier needed — per-wave-private LDS halves)

    // 4x16 lane grid: i = ti + 4*k (k=0..31), j = tj + 16*m (m=0..7).
    const int tj = lane & 15;
    const int ti = lane >> 4;

    // b tile packed as chain-pairs: pair mm covers chains (2mm, 2mm+1),
    // i.e. columns j = tj+16*(2mm) and j = tj+16*(2mm+1). 24 VGPRs.
    f2 bxp[4], byp[4], bzp[4];
    #pragma unroll
    for (int mm = 0; mm < 4; ++mm) {
        const float4 v0 = x2s[w][tj + 32 * mm];
        const float4 v1 = x2s[w][tj + 32 * mm + 16];
        bxp[mm] = (f2){v0.x, v1.x};
        byp[mm] = (f2){v0.y, v1.y};
        bzp[mm] = (f2){v0.z, v1.z};
    }

    // Eight independent (value, k-index) min-chains (scalar tracking).
    float bd[8];
    int   bk[8];
    #pragma unroll
    for (int m = 0; m < 8; ++m) { bd[m] = __builtin_inff(); bk[m] = 0; }

    // Groups of 8 a-points (R5's best grouping) bound register liveness;
    // inside each group, packed dual-f32 arithmetic: for each a-point,
    // 4 packed chain-pair evaluations.
    #pragma unroll 1
    for (int kk = 0; kk < 4; ++kk) {
        #pragma unroll
        for (int u = 0; u < 8; ++u) {
            const int k = kk * 8 + u;
            const float4 av = x1s[w][ti + 4 * k];    // 16-lane broadcast read
            const f2 axp = (f2){av.x, av.x};
            const f2 ayp = (f2){av.y, av.y};
            const f2 azp = (f2){av.z, av.z};
            #pragma unroll
            for (int mm = 0; mm < 4; ++mm) {
                // Packed: two IEEE-rn f32 ops per instruction, no contraction.
                const f2 dx = axp - bxp[mm];
                const f2 dy = ayp - byp[mm];
                const f2 dz = azp - bzp[mm];
                const f2 xx = dx * dx;
                const f2 yy = dy * dy;
                const f2 zz = dz * dz;
                const f2 s  = xx + yy;
                const f2 d2 = s + zz;
                if (d2.x < bd[2 * mm])     { bd[2 * mm]     = d2.x; bk[2 * mm]     = k; }
                if (d2.y < bd[2 * mm + 1]) { bd[2 * mm + 1] = d2.y; bk[2 * mm + 1] = k; }
            }
        }
    }

    // Combine the 8 chains exactly via packed (d2, flat) keys.
    const int base = ti * P + tj;
    unsigned long long key = 0xffffffffffffffffull;
    #pragma unroll
    for (int m = 0; m < 8; ++m) {
        const unsigned flat = (unsigned)(base + (m << 4) + (bk[m] << 9)); // +512*k
        const unsigned long long km =
            ((unsigned long long)__float_as_uint(bd[m]) << 32) | flat;
        if (km < key) key = km;
    }

    // Wave-level (64-lane) min reduce — no cross-wave stage needed.
    for (int off = 32; off > 0; off >>= 1) {
        unsigned long long other = __shfl_down(key, off, 64);
        if (other < key) key = other;
    }

    if (lane == 0) {
        const int flat = (int)(key & 0xffffffffull);
        const int i1 = flat >> 7;
        const int i2 = flat & (P - 1);

        const float v1x = x1s[w][i1].x, v1y = x1s[w][i1].y, v1z = x1s[w][i1].z;
        const float v2x = x2s[w][i2].x, v2y = x2s[w][i2].y, v2z = x2s[w][i2].z;

        const float dx = v1x - v2x, dy = v1y - v2y, dz = v1z - v2z;
        const float lend = sqrtf(dx * dx + dy * dy + dz * dz);

        float nx, ny, nz;
        if (lend > 0.f) { nx = dx / lend; ny = dy / lend; nz = dz / lend; }
        else            { nx = dx;        ny = dy;        nz = dz;        }

        const float B0 = nx * nx, B1 = nx * ny, B2 = nx * nz;
        const float B3 = ny * nx, B4 = ny * ny, B5 = ny * nz;
        const float B6 = nz * nx, B7 = nz * ny, B8 = nz * nz;

        // Row layout (38 floats): [v1 v2 n lend B] [v2 v1 -n lend B].
        // 152-byte rows are 8-aligned every row -> float2 stores are safe.
        float2* o = reinterpret_cast<float2*>(out + (size_t)e * 38);
        o[0]  = make_float2(v1x, v1y);
        o[1]  = make_float2(v1z, v2x);
        o[2]  = make_float2(v2y, v2z);
        o[3]  = make_float2(nx,  ny);
        o[4]  = make_float2(nz,  lend);
        o[5]  = make_float2(B0,  B1);
        o[6]  = make_float2(B2,  B3);
        o[7]  = make_float2(B4,  B5);
        o[8]  = make_float2(B6,  B7);
        o[9]  = make_float2(B8,  v2x);
        o[10] = make_float2(v2y, v2z);
        o[11] = make_float2(v1x, v1y);
        o[12] = make_float2(v1z, -nx);
        o[13] = make_float2(-ny, -nz);
        o[14] = make_float2(lend, B0);
        o[15] = make_float2(B1,  B2);
        o[16] = make_float2(B3,  B4);
        o[17] = make_float2(B5,  B6);
        o[18] = make_float2(B7,  B8);
    }
}

extern "C" void kernel_launch(void* const* d_in, const int* in_sizes, int n_in,
                              void* d_out, int out_size, void* d_ws, size_t ws_size,
                              hipStream_t stream) {
    const float* data       = (const float*)d_in[0];
    const int*   clusts     = (const int*)d_in[1];
    const int*   edge_index = (const int*)d_in[2];
    float*       out        = (float*)d_out;
    float4*      ws         = (float4*)d_ws;

    const size_t need = (size_t)NC * P * sizeof(float4);  // 2 MB
    if (ws_size >= need) {
        gather_kernel<<<(NC * P) / 256, 256, 0, stream>>>(data, clusts, ws);
        clust_geo_edge_kernel<true><<<NE / 2, 128, 0, stream>>>(data, clusts, edge_index, ws, out);
    } else {
        clust_geo_edge_kernel<false><<<NE / 2, 128, 0, stream>>>(data, clusts, edge_index, ws, out);
    }
}